// Round 1
// baseline (2516.391 us; speedup 1.0000x reference)
//
#include <hip/hip_runtime.h>
#include <math.h>

#ifndef __HIP_DEVICE_COMPILE__
#endif

constexpr float WLIM = 5000.0f;
constexpr double RIDGE = 1e-7;

// ---------------- Kernel 1: accumulate symmetric 5x5 moment matrix per node ----------------
__global__ __launch_bounds__(256) void k_accum(const float2* __restrict__ pos,
                                               const int* __restrict__ row,
                                               const int* __restrict__ col,
                                               float* __restrict__ Macc,
                                               int nE) {
    int e = blockIdx.x * blockDim.x + threadIdx.x;
    if (e >= nE) return;
    int r = row[e];
    int c = col[e];
    float2 pc = pos[c];
    float2 pr = pos[r];
    float x = pc.x - pr.x;
    float y = pc.y - pr.y;
    float H[5];
    H[0] = x; H[1] = y; H[2] = x * y; H[3] = x * x; H[4] = y * y;
    float* base = Macc + (size_t)r * 16;
    int idx = 0;
    #pragma unroll
    for (int i = 0; i < 5; ++i) {
        #pragma unroll
        for (int j = i; j < 5; ++j) {
            // native global_atomic_add_f32 (denorm-flush irrelevant here);
            // plain atomicAdd may lower to a CAS loop -> livelock at 32-way contention
            unsafeAtomicAdd(base + idx, H[i] * H[j]);
            ++idx;
        }
    }
}

// ---------------- Kernel 2: per-node 5x5 Cholesky solve in f64 ----------------
__global__ __launch_bounds__(256) void k_solve(const float* __restrict__ Macc,
                                               float* __restrict__ C,
                                               int nN) {
    int n = blockIdx.x * blockDim.x + threadIdx.x;
    if (n >= nN) return;
    const float* base = Macc + (size_t)n * 16;
    double A[5][5];
    {
        int idx = 0;
        #pragma unroll
        for (int i = 0; i < 5; ++i) {
            #pragma unroll
            for (int j = i; j < 5; ++j) {
                double v = (double)base[idx++];
                A[i][j] = v;
                A[j][i] = v;
            }
        }
    }
    #pragma unroll
    for (int i = 0; i < 5; ++i) A[i][i] += RIDGE;

    // Cholesky: A = L L^T, L stored in lower triangle of A (static indices only)
    #pragma unroll
    for (int k = 0; k < 5; ++k) {
        double d = A[k][k];
        d = sqrt(fmax(d, 1e-300));
        A[k][k] = d;
        double inv = 1.0 / d;
        #pragma unroll
        for (int i = k + 1; i < 5; ++i) A[i][k] *= inv;
        #pragma unroll
        for (int j = k + 1; j < 5; ++j) {
            #pragma unroll
            for (int i = j; i < 5; ++i) {
                A[i][j] -= A[i][k] * A[j][k];
            }
        }
    }

    // b = [0,0,0,2,2]; forward solve L y = b
    double b[5] = {0.0, 0.0, 0.0, 2.0, 2.0};
    double y[5];
    #pragma unroll
    for (int i = 0; i < 5; ++i) {
        double s = b[i];
        #pragma unroll
        for (int k = 0; k < 5; ++k) {
            if (k < i) s -= A[i][k] * y[k];
        }
        y[i] = s / A[i][i];
    }
    // back solve L^T x = y
    double xs[5];
    #pragma unroll
    for (int ii = 4; ii >= 0; --ii) {
        double s = y[ii];
        #pragma unroll
        for (int k = 0; k < 5; ++k) {
            if (k > ii) s -= A[k][ii] * xs[k];
        }
        xs[ii] = s / A[ii][ii];
    }

    float* cbase = C + (size_t)n * 8;
    #pragma unroll
    for (int i = 0; i < 5; ++i) cbase[i] = (float)xs[i];
    #pragma unroll
    for (int i = 5; i < 8; ++i) cbase[i] = 0.0f;
}

// ---------------- Kernel 3: per-edge weight = <C[row], H>, clipped ----------------
__global__ __launch_bounds__(256) void k_weights(const float2* __restrict__ pos,
                                                 const int* __restrict__ row,
                                                 const int* __restrict__ col,
                                                 const float* __restrict__ C,
                                                 float* __restrict__ out,
                                                 int nE) {
    int e = blockIdx.x * blockDim.x + threadIdx.x;
    if (e >= nE) return;
    int r = row[e];
    int c = col[e];
    float2 pc = pos[c];
    float2 pr = pos[r];
    float x = pc.x - pr.x;
    float y = pc.y - pr.y;
    const float4* cq = (const float4*)(C + (size_t)r * 8);
    float4 c0 = cq[0];
    float c4 = C[(size_t)r * 8 + 4];
    float w = c0.x * x + c0.y * y + c0.z * (x * y) + c0.w * (x * x) + c4 * (y * y);
    w = fminf(fmaxf(w, -WLIM), WLIM);
    out[e] = w;
}

extern "C" void kernel_launch(void* const* d_in, const int* in_sizes, int n_in,
                              void* d_out, int out_size, void* d_ws, size_t ws_size,
                              hipStream_t stream) {
    const float2* pos = (const float2*)d_in[0];
    const int* ei = (const int*)d_in[1];
    const int nN = in_sizes[0] / 2;      // (N,2) f32
    const int nE = in_sizes[1] / 2;      // (2,E) int32
    const int* row = ei;
    const int* col = ei + nE;

    float* Macc = (float*)d_ws;                      // nN*16 floats
    float* C = Macc + (size_t)nN * 16;               // nN*8 floats
    float* out = (float*)d_out;

    hipMemsetAsync(Macc, 0, (size_t)nN * 16 * sizeof(float), stream);

    int tb = 256;
    k_accum<<<(nE + tb - 1) / tb, tb, 0, stream>>>(pos, row, col, Macc, nE);
    k_solve<<<(nN + tb - 1) / tb, tb, 0, stream>>>(Macc, C, nN);
    k_weights<<<(nE + tb - 1) / tb, tb, 0, stream>>>(pos, row, col, C, out, nE);
}

// Round 2
// 652.872 us; speedup vs baseline: 3.8543x; 3.8543x over previous
//
#include <hip/hip_runtime.h>
#include <math.h>

constexpr float WLIM = 5000.0f;
constexpr double RIDGE = 1e-7;

// ---------------- Kernel 1: histogram of row -> cnt ----------------
__global__ __launch_bounds__(256) void k_hist(const int* __restrict__ row,
                                              int* __restrict__ cnt, int nE) {
    int e = blockIdx.x * blockDim.x + threadIdx.x;
    if (e < nE) atomicAdd(&cnt[row[e]], 1);
}

// ---------------- Kernel 2: exclusive scan of cnt -> offs, copy -> cursor ----
// Single block, 1024 threads, 4 elements/thread/tile. ~25 tiles for 100K.
__global__ __launch_bounds__(1024) void k_scan(const int* __restrict__ cnt,
                                               int* __restrict__ offs,
                                               int* __restrict__ cursor,
                                               int nN) {
    __shared__ int wtot[16];
    __shared__ int wpref[16];
    __shared__ int carry_tot;
    const int tid = threadIdx.x;
    const int lane = tid & 63;
    const int wid = tid >> 6;
    int carry = 0;
    const int TILE = 4096;
    for (int base = 0; base < nN; base += TILE) {
        int i0 = base + tid * 4;
        int v[4];
        #pragma unroll
        for (int k = 0; k < 4; ++k) {
            int i = i0 + k;
            v[k] = (i < nN) ? cnt[i] : 0;
        }
        int s = v[0] + v[1] + v[2] + v[3];
        // wave-inclusive scan of per-thread sums (wave64, no barriers)
        int x = s;
        #pragma unroll
        for (int d = 1; d < 64; d <<= 1) {
            int t = __shfl_up(x, d);
            if (lane >= d) x += t;
        }
        if (lane == 63) wtot[wid] = x;
        __syncthreads();
        if (tid == 0) {
            int a = 0;
            #pragma unroll
            for (int w = 0; w < 16; ++w) { wpref[w] = a; a += wtot[w]; }
            carry_tot = a;
        }
        __syncthreads();
        int excl = carry + wpref[wid] + (x - s);  // exclusive offset of this thread's group
        int run = excl;
        #pragma unroll
        for (int k = 0; k < 4; ++k) {
            int i = i0 + k;
            if (i < nN) { offs[i] = run; cursor[i] = run; }
            run += v[k];
        }
        carry += carry_tot;
        __syncthreads();  // protect wtot/carry_tot before next tile overwrites
    }
    if (tid == 0) offs[nN] = carry;  // == nE
}

// ---------------- Kernel 3: scatter edge ids into CSR order (into d_out as int scratch) ----
__global__ __launch_bounds__(256) void k_scatter(const int* __restrict__ row,
                                                 int* __restrict__ cursor,
                                                 int* __restrict__ sorted, int nE) {
    int e = blockIdx.x * blockDim.x + threadIdx.x;
    if (e >= nE) return;
    int p = atomicAdd(&cursor[row[e]], 1);
    sorted[p] = e;
}

// ---------------- Kernel 4: per-node register accumulation + f64 Cholesky solve ----
__global__ __launch_bounds__(256) void k_node(const float2* __restrict__ pos,
                                              const int* __restrict__ col,
                                              const int* __restrict__ offs,
                                              const int* __restrict__ sorted,
                                              float* __restrict__ C, int nN) {
    int n = blockIdx.x * blockDim.x + threadIdx.x;
    if (n >= nN) return;
    int s = offs[n];
    int epd = offs[n + 1];
    float2 pr = pos[n];
    float m[15];
    #pragma unroll
    for (int i = 0; i < 15; ++i) m[i] = 0.0f;
    for (int t = s; t < epd; ++t) {
        int e = sorted[t];
        float2 pc = pos[col[e]];
        float x = pc.x - pr.x;
        float y = pc.y - pr.y;
        float xy = x * y, xx = x * x, yy = y * y;
        // H = [x, y, xy, xx, yy]; upper triangle, row-major (i<=j)
        m[0]  += x * x;   m[1]  += x * y;   m[2]  += x * xy;  m[3]  += x * xx;  m[4]  += x * yy;
        m[5]  += y * y;   m[6]  += y * xy;  m[7]  += y * xx;  m[8]  += y * yy;
        m[9]  += xy * xy; m[10] += xy * xx; m[11] += xy * yy;
        m[12] += xx * xx; m[13] += xx * yy;
        m[14] += yy * yy;
    }

    double A[5][5];
    {
        int idx = 0;
        #pragma unroll
        for (int i = 0; i < 5; ++i) {
            #pragma unroll
            for (int j = i; j < 5; ++j) {
                double v = (double)m[idx++];
                A[i][j] = v;
                A[j][i] = v;
            }
        }
    }
    #pragma unroll
    for (int i = 0; i < 5; ++i) A[i][i] += RIDGE;

    // Cholesky (static indices only)
    #pragma unroll
    for (int k = 0; k < 5; ++k) {
        double d = A[k][k];
        d = sqrt(fmax(d, 1e-300));
        A[k][k] = d;
        double inv = 1.0 / d;
        #pragma unroll
        for (int i = k + 1; i < 5; ++i) A[i][k] *= inv;
        #pragma unroll
        for (int j = k + 1; j < 5; ++j) {
            #pragma unroll
            for (int i = j; i < 5; ++i) A[i][j] -= A[i][k] * A[j][k];
        }
    }
    // b = [0,0,0,2,2]; L y = b
    double b[5] = {0.0, 0.0, 0.0, 2.0, 2.0};
    double y[5];
    #pragma unroll
    for (int i = 0; i < 5; ++i) {
        double sv = b[i];
        #pragma unroll
        for (int k = 0; k < 5; ++k) {
            if (k < i) sv -= A[i][k] * y[k];
        }
        y[i] = sv / A[i][i];
    }
    // L^T x = y
    double xs[5];
    #pragma unroll
    for (int ii = 4; ii >= 0; --ii) {
        double sv = y[ii];
        #pragma unroll
        for (int k = 0; k < 5; ++k) {
            if (k > ii) sv -= A[k][ii] * xs[k];
        }
        xs[ii] = sv / A[ii][ii];
    }

    float* cbase = C + (size_t)n * 8;
    #pragma unroll
    for (int i = 0; i < 5; ++i) cbase[i] = (float)xs[i];
    #pragma unroll
    for (int i = 5; i < 8; ++i) cbase[i] = 0.0f;
}

// ---------------- Kernel 5: per-edge weight = <C[row], H>, clipped (overwrites d_out) ----
__global__ __launch_bounds__(256) void k_weights(const float2* __restrict__ pos,
                                                 const int* __restrict__ row,
                                                 const int* __restrict__ col,
                                                 const float* __restrict__ C,
                                                 float* __restrict__ out,
                                                 int nE) {
    int e = blockIdx.x * blockDim.x + threadIdx.x;
    if (e >= nE) return;
    int r = row[e];
    int c = col[e];
    float2 pc = pos[c];
    float2 pr = pos[r];
    float x = pc.x - pr.x;
    float y = pc.y - pr.y;
    const float4* cq = (const float4*)(C + (size_t)r * 8);
    float4 c0 = cq[0];
    float c4 = C[(size_t)r * 8 + 4];
    float w = c0.x * x + c0.y * y + c0.z * (x * y) + c0.w * (x * x) + c4 * (y * y);
    w = fminf(fmaxf(w, -WLIM), WLIM);
    out[e] = w;
}

extern "C" void kernel_launch(void* const* d_in, const int* in_sizes, int n_in,
                              void* d_out, int out_size, void* d_ws, size_t ws_size,
                              hipStream_t stream) {
    const float2* pos = (const float2*)d_in[0];
    const int* ei = (const int*)d_in[1];
    const int nN = in_sizes[0] / 2;   // (N,2) f32
    const int nE = in_sizes[1] / 2;   // (2,E) int32
    const int* row = ei;
    const int* col = ei + nE;

    // workspace layout (needs ~4.6MB; 9.6MB proven available in R1)
    int* cnt = (int*)d_ws;                 // nN
    int* offs = cnt + nN;                  // nN+1
    int* cursor = offs + nN + 1;           // nN
    float* C = (float*)(cursor + nN);      // nN*8 floats

    int* sorted = (int*)d_out;             // nE ints, overwritten by k_weights at the end
    float* out = (float*)d_out;

    hipMemsetAsync(cnt, 0, (size_t)nN * sizeof(int), stream);

    const int tb = 256;
    const int egrid = (nE + tb - 1) / tb;
    k_hist<<<egrid, tb, 0, stream>>>(row, cnt, nE);
    k_scan<<<1, 1024, 0, stream>>>(cnt, offs, cursor, nN);
    k_scatter<<<egrid, tb, 0, stream>>>(row, cursor, sorted, nE);
    k_node<<<(nN + tb - 1) / tb, tb, 0, stream>>>(pos, col, offs, sorted, C, nN);
    k_weights<<<egrid, tb, 0, stream>>>(pos, row, col, C, out, nE);
}

// Round 3
// 294.388 us; speedup vs baseline: 8.5479x; 2.2177x over previous
//
#include <hip/hip_runtime.h>
#include <math.h>

constexpr float WLIM = 5000.0f;
constexpr double RIDGE = 1e-7;

// ---------------- Kernel 1: build per-node linked lists of edges ----------------
// head[r] = last edge seen with row r; next[e] = previous head. next is COALESCED.
__global__ __launch_bounds__(256) void k_build(const int* __restrict__ row,
                                               int* __restrict__ head,
                                               int* __restrict__ nxt, int nE) {
    int e = blockIdx.x * blockDim.x + threadIdx.x;
    if (e >= nE) return;
    int r = row[e];
    int old = atomicExch(&head[r], e);
    nxt[e] = old;
}

// ---------------- Kernel 2: traverse list, accumulate 5x5 moments, f64 Cholesky ----
__global__ __launch_bounds__(256) void k_node(const float2* __restrict__ pos,
                                              const int* __restrict__ col,
                                              const int* __restrict__ head,
                                              const int* __restrict__ nxt,
                                              float* __restrict__ C, int nN) {
    int n = blockIdx.x * blockDim.x + threadIdx.x;
    if (n >= nN) return;
    float2 pr = pos[n];
    float m[15];
    #pragma unroll
    for (int i = 0; i < 15; ++i) m[i] = 0.0f;

    int e = head[n];
    while (e >= 0) {
        int c = col[e];       // independent gathers: issue both, one hop latency
        int nx = nxt[e];
        float2 pc = pos[c];
        float x = pc.x - pr.x;
        float y = pc.y - pr.y;
        float xy = x * y, xx = x * x, yy = y * y;
        // H = [x, y, xy, xx, yy]; upper triangle, row-major (i<=j)
        m[0]  += x * x;   m[1]  += x * y;   m[2]  += x * xy;  m[3]  += x * xx;  m[4]  += x * yy;
        m[5]  += y * y;   m[6]  += y * xy;  m[7]  += y * xx;  m[8]  += y * yy;
        m[9]  += xy * xy; m[10] += xy * xx; m[11] += xy * yy;
        m[12] += xx * xx; m[13] += xx * yy;
        m[14] += yy * yy;
        e = nx;
    }

    double A[5][5];
    {
        int idx = 0;
        #pragma unroll
        for (int i = 0; i < 5; ++i) {
            #pragma unroll
            for (int j = i; j < 5; ++j) {
                double v = (double)m[idx++];
                A[i][j] = v;
                A[j][i] = v;
            }
        }
    }
    #pragma unroll
    for (int i = 0; i < 5; ++i) A[i][i] += RIDGE;

    // Cholesky (static indices only)
    #pragma unroll
    for (int k = 0; k < 5; ++k) {
        double d = A[k][k];
        d = sqrt(fmax(d, 1e-300));
        A[k][k] = d;
        double inv = 1.0 / d;
        #pragma unroll
        for (int i = k + 1; i < 5; ++i) A[i][k] *= inv;
        #pragma unroll
        for (int j = k + 1; j < 5; ++j) {
            #pragma unroll
            for (int i = j; i < 5; ++i) A[i][j] -= A[i][k] * A[j][k];
        }
    }
    // b = [0,0,0,2,2]; L y = b
    double b[5] = {0.0, 0.0, 0.0, 2.0, 2.0};
    double y[5];
    #pragma unroll
    for (int i = 0; i < 5; ++i) {
        double sv = b[i];
        #pragma unroll
        for (int k = 0; k < 5; ++k) {
            if (k < i) sv -= A[i][k] * y[k];
        }
        y[i] = sv / A[i][i];
    }
    // L^T x = y
    double xs[5];
    #pragma unroll
    for (int ii = 4; ii >= 0; --ii) {
        double sv = y[ii];
        #pragma unroll
        for (int k = 0; k < 5; ++k) {
            if (k > ii) sv -= A[k][ii] * xs[k];
        }
        xs[ii] = sv / A[ii][ii];
    }

    float* cbase = C + (size_t)n * 8;
    #pragma unroll
    for (int i = 0; i < 5; ++i) cbase[i] = (float)xs[i];
    #pragma unroll
    for (int i = 5; i < 8; ++i) cbase[i] = 0.0f;
}

// ---------------- Kernel 3: per-edge weight = <C[row], H>, clipped (overwrites d_out) ----
__global__ __launch_bounds__(256) void k_weights(const float2* __restrict__ pos,
                                                 const int* __restrict__ row,
                                                 const int* __restrict__ col,
                                                 const float* __restrict__ C,
                                                 float* __restrict__ out,
                                                 int nE) {
    int e = blockIdx.x * blockDim.x + threadIdx.x;
    if (e >= nE) return;
    int r = row[e];
    int c = col[e];
    float2 pc = pos[c];
    float2 pr = pos[r];
    float x = pc.x - pr.x;
    float y = pc.y - pr.y;
    const float4* cq = (const float4*)(C + (size_t)r * 8);
    float4 c0 = cq[0];
    float c4 = C[(size_t)r * 8 + 4];
    float w = c0.x * x + c0.y * y + c0.z * (x * y) + c0.w * (x * x) + c4 * (y * y);
    w = fminf(fmaxf(w, -WLIM), WLIM);
    out[e] = w;
}

extern "C" void kernel_launch(void* const* d_in, const int* in_sizes, int n_in,
                              void* d_out, int out_size, void* d_ws, size_t ws_size,
                              hipStream_t stream) {
    const float2* pos = (const float2*)d_in[0];
    const int* ei = (const int*)d_in[1];
    const int nN = in_sizes[0] / 2;   // (N,2) f32
    const int nE = in_sizes[1] / 2;   // (2,E) int32
    const int* row = ei;
    const int* col = ei + nE;

    // workspace: head (nN ints) + C (nN*8 floats)  ~= 3.6MB
    int* head = (int*)d_ws;
    float* C = (float*)(head + nN);

    // next[] lives in d_out (nE ints fit exactly in nE floats); it is fully
    // consumed by k_node before k_weights overwrites d_out with the result.
    int* nxt = (int*)d_out;
    float* out = (float*)d_out;

    hipMemsetAsync(head, 0xFF, (size_t)nN * sizeof(int), stream);  // head = -1

    const int tb = 256;
    const int egrid = (nE + tb - 1) / tb;
    k_build<<<egrid, tb, 0, stream>>>(row, head, nxt, nE);
    k_node<<<(nN + tb - 1) / tb, tb, 0, stream>>>(pos, col, head, nxt, C, nN);
    k_weights<<<egrid, tb, 0, stream>>>(pos, row, col, C, out, nE);
}